// Round 14
// baseline (35.490 us; speedup 1.0000x reference)
//
#include <hip/hip_runtime.h>
#include <stdint.h>

#define N_TOK 4096
#define D_IN  64
#define NF    32
#define NH    4
#define OUTW  (NH * NF)        // 128
#define NT    8
#define CHUNK 128              // n per chunk (4 k-steps of 32)
#define BT    32               // rows per block (2 rowgroups of 16)

typedef float        f32x4  __attribute__((ext_vector_type(4)));
typedef unsigned int uint4v __attribute__((ext_vector_type(4)));
typedef __bf16       bf16x8 __attribute__((ext_vector_type(8)));

union Frag { uint4v u; bf16x8 v; };

static __device__ __forceinline__ unsigned short f2bf_rne(float x) {
  unsigned u = __float_as_uint(x);
  u += 0x7fffu + ((u >> 16) & 1u);
  return (unsigned short)(u >> 16);
}
static __device__ __forceinline__ float bflo(unsigned x) {
  return __uint_as_float(x << 16);
}
static __device__ __forceinline__ float bfhi(unsigned x) {
  return __uint_as_float(x & 0xffff0000u);
}

// ---------- Kernel 1: PB = WG2 fragment-packed (8 sets), EDH[h][n] ----------
// PB 16-B slot ((t*8 + set)*64 + gq*16 + col): t = n>>5, gq = (n>>3)&3,
// set = h*2 + fhalf, col = f&15, 8 bf16 (j = n&7). Total 1 MB.
__global__ __launch_bounds__(128) void prep_kernel(
    const float* __restrict__ G, const float* __restrict__ W,
    const float* __restrict__ bias, const float* __restrict__ a_dst,
    unsigned short* __restrict__ EDH, unsigned short* __restrict__ PB) {
  __shared__ float gs[NT * D_IN];
  const int tid = threadIdx.x;
  const int n0  = blockIdx.x * NT;
  {
    const float4* src = (const float4*)(G + (size_t)n0 * D_IN);
    float4* dst = (float4*)gs;
    dst[tid] = src[tid];
  }
  __syncthreads();
  const int h = tid >> 5, f = tid & 31;
  float acc[NT];
  const float bb = bias[h * NF + f];
#pragma unroll
  for (int k = 0; k < NT; ++k) acc[k] = bb;
#pragma unroll
  for (int i = 0; i < D_IN; ++i) {
    const float wv = W[(h * D_IN + i) * NF + f];
#pragma unroll
    for (int k = 0; k < NT; ++k) acc[k] = fmaf(gs[k * D_IN + i], wv, acc[k]);
  }
  const float ad = a_dst[h * NF + f];
  float ev[NT];
#pragma unroll
  for (int k = 0; k < NT; ++k) {
    float s = acc[k] * ad;
    s += __shfl_xor(s, 1);  s += __shfl_xor(s, 2);  s += __shfl_xor(s, 4);
    s += __shfl_xor(s, 8);  s += __shfl_xor(s, 16);
    ev[k] = __expf(s);
  }
  const int t   = n0 >> 5;
  const int gq  = (n0 >> 3) & 3;
  const int set = (h << 1) | (f >> 4);
  const int col = f & 15;
  union { uint4 u4; unsigned short us[8]; } pk;
#pragma unroll
  for (int k = 0; k < NT; ++k) pk.us[k] = f2bf_rne(acc[k] * ev[k]);
  *(uint4*)(PB + (size_t)((((t * 8 + set) << 6) + (gq << 4) + col)) * 8) = pk.u4;
  if (f == 0) {
    union { uint4 u4; unsigned short us[8]; } pe;
#pragma unroll
    for (int k = 0; k < NT; ++k) pe.us[k] = f2bf_rne(ev[k]);
    *(uint4*)&EDH[(size_t)h * N_TOK + n0] = pe.u4;
  }
}

// ---------- Kernel 2: r12 structure, single delta = A prefetch distance 2 ---
// grid = (4096/32)*NS, 512 thr (8 waves = sets). 4 A reg-buffers (3 chunks in
// flight): ITER(c) uses A(c+1) (issued 2 iters ago >= HBM latency), loads
// A(c+3); vmcnt(8). B double-buffered at distance 1 (L2). Unroll x4.
template <int NS>
__global__ __launch_bounds__(512) void attn_kernel(
    const float* __restrict__ A, const unsigned short* __restrict__ EDH,
    const unsigned short* __restrict__ PB, float* __restrict__ op,
    float* __restrict__ dp, float* __restrict__ out) {
  constexpr int NHALF  = N_TOK / NS;
  constexpr int NIT    = NHALF / CHUNK;
  constexpr int RINGSZ = BT * CHUNK * 2;                         // 8192 B
  __shared__ __align__(16) unsigned short ring[3 * BT * CHUNK];  // 24 KB
  __shared__ __align__(16) unsigned short EDt[NH * NHALF];       // 8 KB @NS=4
  __shared__ float denLds[BT * NH];                              // 512 B
  char* ringb = (char*)ring;

  const int tid  = threadIdx.x;
  const int lane = tid & 63;
  const int w    = tid >> 6;
  const int bid  = blockIdx.x;
  const int s    = bid & (NS - 1);
  const int b0   = (bid / NS) * BT;

  // staging coords: 512 thr = 32 rows x 16 col-groups of 8
  const int srow = tid >> 4, tp = tid & 15;
  const float* abase = A + (size_t)(b0 + srow) * N_TOK + s * NHALF + tp * 8;
  const int wb0 = srow * 256 + ((tp ^ (srow & 15)) << 4);  // swizzled 16-B slot

  // MFMA frag coords
  const int rowm = lane & 15, g = lane >> 4;
  const char* pbb  = (const char*)PB + (size_t)s * (NHALF / 32) * 8192;
  const char* pown = pbb + (((w << 6) + lane) << 4);

  { // EDH[h][s*NHALF ..] -> EDt[h][0..NHALF)
    const uint4* src = (const uint4*)EDH;
    uint4* dst = (uint4*)EDt;
    constexpr int tot = NH * NHALF / 8;
#pragma unroll 1
    for (int i = tid; i < tot; i += 512) {
      const int hh = i / (NHALF / 8), k = i % (NHALF / 8);
      dst[i] = src[hh * (N_TOK / 8) + s * (NHALF / 8) + k];
    }
  }
  __syncthreads();

  f32x4 acc0 = {0.f, 0.f, 0.f, 0.f}, acc1 = {0.f, 0.f, 0.f, 0.f};
  f32x4 dsum = {0.f, 0.f, 0.f, 0.f};
  f32x4 aWa, aWb, aXa, aXb, aYa, aYb, aZa, aZb;  // 4 A chunk buffers
  Frag bo0, bo1, bo2, bo3, co0, co1, co2, co3;
  int mR = 0, mW = 1;

#define LOADA2(d0, d1, cc) do {                                                \
    const float* ap_ = abase + (size_t)(cc) * CHUNK;                           \
    asm volatile("global_load_dwordx4 %0, %1, off"                            \
                 : "=v"(d0) : "v"(ap_) : "memory");                            \
    asm volatile("global_load_dwordx4 %0, %1, off"                            \
                 : "=v"(d1) : "v"(ap_ + 4) : "memory");                        \
  } while (0)
#define LOADB(fr, cc, kk)                                                      \
  asm volatile("global_load_dwordx4 %0, %1, off"                              \
               : "=v"(fr.u)                                                    \
               : "v"(pown + (size_t)((cc) * 4 + (kk)) * 8192) : "memory")

// exp + (guarded) den-FMA vs EDt broadcast reads + bf16 pack + swizzled write
#define EXPP(AV0, AV1, cchunk, mw) do {                                        \
    float x0 = __expf(-AV0[0]), x1 = __expf(-AV0[1]);                          \
    float x2 = __expf(-AV0[2]), x3 = __expf(-AV0[3]);                          \
    float x4 = __expf(-AV1[0]), x5 = __expf(-AV1[1]);                          \
    float x6 = __expf(-AV1[2]), x7 = __expf(-AV1[3]);                          \
    if ((cchunk) < NIT) {                                                      \
      const int eo_ = (cchunk) * CHUNK + tp * 8;                               \
      uint4v e0_ = *(const uint4v*)&EDt[0 * NHALF + eo_];                      \
      uint4v e1_ = *(const uint4v*)&EDt[1 * NHALF + eo_];                      \
      uint4v e2_ = *(const uint4v*)&EDt[2 * NHALF + eo_];                      \
      uint4v e3_ = *(const uint4v*)&EDt[3 * NHALF + eo_];                      \
      dsum[0] = fmaf(x0, bflo(e0_[0]), dsum[0]);                               \
      dsum[0] = fmaf(x1, bfhi(e0_[0]), dsum[0]);                               \
      dsum[0] = fmaf(x2, bflo(e0_[1]), dsum[0]);                               \
      dsum[0] = fmaf(x3, bfhi(e0_[1]), dsum[0]);                               \
      dsum[0] = fmaf(x4, bflo(e0_[2]), dsum[0]);                               \
      dsum[0] = fmaf(x5, bfhi(e0_[2]), dsum[0]);                               \
      dsum[0] = fmaf(x6, bflo(e0_[3]), dsum[0]);                               \
      dsum[0] = fmaf(x7, bfhi(e0_[3]), dsum[0]);                               \
      dsum[1] = fmaf(x0, bflo(e1_[0]), dsum[1]);                               \
      dsum[1] = fmaf(x1, bfhi(e1_[0]), dsum[1]);                               \
      dsum[1] = fmaf(x2, bflo(e1_[1]), dsum[1]);                               \
      dsum[1] = fmaf(x3, bfhi(e1_[1]), dsum[1]);                               \
      dsum[1] = fmaf(x4, bflo(e1_[2]), dsum[1]);                               \
      dsum[1] = fmaf(x5, bfhi(e1_[2]), dsum[1]);                               \
      dsum[1] = fmaf(x6, bflo(e1_[3]), dsum[1]);                               \
      dsum[1] = fmaf(x7, bfhi(e1_[3]), dsum[1]);                               \
      dsum[2] = fmaf(x0, bflo(e2_[0]), dsum[2]);                               \
      dsum[2] = fmaf(x1, bfhi(e2_[0]), dsum[2]);                               \
      dsum[2] = fmaf(x2, bflo(e2_[1]), dsum[2]);                               \
      dsum[2] = fmaf(x3, bfhi(e2_[1]), dsum[2]);                               \
      dsum[2] = fmaf(x4, bflo(e2_[2]), dsum[2]);                               \
      dsum[2] = fmaf(x5, bfhi(e2_[2]), dsum[2]);                               \
      dsum[2] = fmaf(x6, bflo(e2_[3]), dsum[2]);                               \
      dsum[2] = fmaf(x7, bfhi(e2_[3]), dsum[2]);                               \
      dsum[3] = fmaf(x0, bflo(e3_[0]), dsum[3]);                               \
      dsum[3] = fmaf(x1, bfhi(e3_[0]), dsum[3]);                               \
      dsum[3] = fmaf(x2, bflo(e3_[1]), dsum[3]);                               \
      dsum[3] = fmaf(x3, bfhi(e3_[1]), dsum[3]);                               \
      dsum[3] = fmaf(x4, bflo(e3_[2]), dsum[3]);                               \
      dsum[3] = fmaf(x5, bfhi(e3_[2]), dsum[3]);                               \
      dsum[3] = fmaf(x6, bflo(e3_[3]), dsum[3]);                               \
      dsum[3] = fmaf(x7, bfhi(e3_[3]), dsum[3]);                               \
    }                                                                          \
    uint4v t_;                                                                 \
    t_[0] = __builtin_amdgcn_perm(__float_as_uint(x1), __float_as_uint(x0), 0x07060302u); \
    t_[1] = __builtin_amdgcn_perm(__float_as_uint(x3), __float_as_uint(x2), 0x07060302u); \
    t_[2] = __builtin_amdgcn_perm(__float_as_uint(x5), __float_as_uint(x4), 0x07060302u); \
    t_[3] = __builtin_amdgcn_perm(__float_as_uint(x7), __float_as_uint(x6), 0x07060302u); \
    *(uint4v*)(ringb + (mw) * RINGSZ + wb0) = t_;                              \
  } while (0)

#define MSTEP(rg, kk, FB) do {                                                 \
    Frag af_;                                                                  \
    af_.v = *(const bf16x8*)(ringb + mR * RINGSZ + ((rg) * 16 + rowm) * 256 +  \
                             ((((kk) * 4 + g) ^ rowm) << 4));                  \
    if ((rg) == 0)                                                             \
      acc0 = __builtin_amdgcn_mfma_f32_16x16x32_bf16(af_.v, FB.v, acc0, 0, 0, 0); \
    else                                                                       \
      acc1 = __builtin_amdgcn_mfma_f32_16x16x32_bf16(af_.v, FB.v, acc1, 0, 0, 0); \
  } while (0)

// entry queue (old->new): [A(c+1)x2, B(c)x4, A(c+2)x2] = 8.
// issue B(c+1)x4 + A(c+3)x2 -> 14; vmcnt(8) drains A(c+1)+B(c).
// A(c+1) was issued 2 iterations ago (covers ~900cy HBM latency).
#define ITER(cc, AU0, AU1, AL0, AL1, CO0, CO1, CO2, CO3,                       \
             NO0, NO1, NO2, NO3) do {                                          \
    { const int cb_ = ((cc) + 1 < NIT) ? (cc) + 1 : NIT - 1;                   \
      LOADB(NO0, cb_, 0); LOADB(NO1, cb_, 1);                                  \
      LOADB(NO2, cb_, 2); LOADB(NO3, cb_, 3); }                                \
    { const int ca_ = ((cc) + 3 < NIT) ? (cc) + 3 : NIT - 1;                   \
      LOADA2(AL0, AL1, ca_); }                                                 \
    asm volatile("s_waitcnt vmcnt(8)" ::: "memory");                           \
    __builtin_amdgcn_sched_barrier(0);                                         \
    EXPP(AU0, AU1, (cc) + 1, mW);                                              \
    asm volatile("s_waitcnt lgkmcnt(0)" ::: "memory");                         \
    __builtin_amdgcn_sched_barrier(0);                                         \
    __builtin_amdgcn_s_barrier();                                              \
    MSTEP(0, 0, CO0); MSTEP(1, 0, CO0);                                        \
    MSTEP(0, 1, CO1); MSTEP(1, 1, CO1);                                        \
    MSTEP(0, 2, CO2); MSTEP(1, 2, CO2);                                        \
    MSTEP(0, 3, CO3); MSTEP(1, 3, CO3);                                        \
    mR = mW; mW = (mW + 1 == 3) ? 0 : mW + 1;                                  \
  } while (0)

  // prologue: A(0)->aW, A(1)->aX, B(0)->bo, A(2)->aY = 10 outstanding;
  // vmcnt(8) drains A(0); exp chunk 0 into ring[0].
  LOADA2(aWa, aWb, 0);
  LOADA2(aXa, aXb, (1 < NIT) ? 1 : NIT - 1);
  LOADB(bo0, 0, 0); LOADB(bo1, 0, 1); LOADB(bo2, 0, 2); LOADB(bo3, 0, 3);
  LOADA2(aYa, aYb, (2 < NIT) ? 2 : NIT - 1);
  asm volatile("s_waitcnt vmcnt(8)" ::: "memory");
  __builtin_amdgcn_sched_barrier(0);
  EXPP(aWa, aWb, 0, 0);

  // iter c uses A buffer holding chunk c+1, loads chunk c+3; period 4.
#pragma unroll 1
  for (int i = 0; i < NIT; i += 4) {
    ITER(i,     aXa, aXb, aZa, aZb, bo0, bo1, bo2, bo3, co0, co1, co2, co3);
    ITER(i + 1, aYa, aYb, aWa, aWb, co0, co1, co2, co3, bo0, bo1, bo2, bo3);
    ITER(i + 2, aZa, aZb, aXa, aXb, bo0, bo1, bo2, bo3, co0, co1, co2, co3);
    ITER(i + 3, aWa, aWb, aYa, aYb, co0, co1, co2, co3, bo0, bo1, bo2, bo3);
  }

  // drain in-flight asm loads before epilogue reuses their dest regs
  asm volatile("s_waitcnt vmcnt(0)" ::: "memory");
  __builtin_amdgcn_sched_barrier(0);

  // denominator: reduce over the 16 threads (tp) sharing a row
#pragma unroll
  for (int m = 1; m <= 8; m <<= 1) {
    dsum[0] += __shfl_xor(dsum[0], m);
    dsum[1] += __shfl_xor(dsum[1], m);
    dsum[2] += __shfl_xor(dsum[2], m);
    dsum[3] += __shfl_xor(dsum[3], m);
  }

  // C/D: row = rg*16 + g*4 + r, col = rowm. Wave w -> output cols w*16+rowm.
  if (NS == 1) {
    if (tp == 0) {
      float4 dv; dv.x = dsum[0]; dv.y = dsum[1]; dv.z = dsum[2]; dv.w = dsum[3];
      *(float4*)&denLds[srow * NH] = dv;
    }
    __syncthreads();
    const int hh = w >> 1;
#pragma unroll
    for (int r = 0; r < 4; ++r) {
      const int rr = g * 4 + r;
      float o;
      o = acc0[r] / denLds[rr * NH + hh];
      out[(size_t)(b0 + rr) * OUTW + w * 16 + rowm] = o > 0.f ? o : 0.f;
      o = acc1[r] / denLds[(16 + rr) * NH + hh];
      out[(size_t)(b0 + 16 + rr) * OUTW + w * 16 + rowm] = o > 0.f ? o : 0.f;
    }
  } else {
    if (tp == 0) {
      float4 dv; dv.x = dsum[0]; dv.y = dsum[1]; dv.z = dsum[2]; dv.w = dsum[3];
      *(float4*)&dp[((size_t)s * N_TOK + b0 + srow) * NH] = dv;
    }
    float* ob = op + (size_t)s * (N_TOK * OUTW) + (size_t)b0 * OUTW + w * 16 + rowm;
#pragma unroll
    for (int r = 0; r < 4; ++r) {
      const int rr = g * 4 + r;
      ob[(size_t)rr * OUTW]        = acc0[r];
      ob[(size_t)(16 + rr) * OUTW] = acc1[r];
    }
  }
#undef LOADA2
#undef LOADB
#undef EXPP
#undef MSTEP
#undef ITER
}

// ---------- Kernel 3: combine splits, divide, relu ----------
__global__ __launch_bounds__(256) void comb_kernel(
    const float* __restrict__ op, const float* __restrict__ dp,
    float* __restrict__ out, int NS) {
  const int idx4 = blockIdx.x * 256 + threadIdx.x;
  const int eb = idx4 >> 5;
  const int h  = ((idx4 << 2) & 127) >> 5;
  float4 o; o.x = 0.f; o.y = 0.f; o.z = 0.f; o.w = 0.f;
  float d = 0.f;
  for (int s2 = 0; s2 < NS; ++s2) {
    float4 vv = *(const float4*)(op + (size_t)s2 * (N_TOK * OUTW) + (size_t)idx4 * 4);
    o.x += vv.x; o.y += vv.y; o.z += vv.z; o.w += vv.w;
    d += dp[((size_t)s2 * N_TOK + eb) * NH + h];
  }
  const float r = 1.f / d;
  float4 res;
  res.x = fmaxf(o.x * r, 0.f);
  res.y = fmaxf(o.y * r, 0.f);
  res.z = fmaxf(o.z * r, 0.f);
  res.w = fmaxf(o.w * r, 0.f);
  *(float4*)(out + (size_t)idx4 * 4) = res;
}

extern "C" void kernel_launch(void* const* d_in, const int* in_sizes, int n_in,
                              void* d_out, int out_size, void* d_ws, size_t ws_size,
                              hipStream_t stream) {
  // inputs: 0=X(unused) 1=G 2=A 3=W 4=b 5=a_src(unused) 6=a_dst 7=att_b(unused)
  const float* G     = (const float*)d_in[1];
  const float* A     = (const float*)d_in[2];
  const float* W     = (const float*)d_in[3];
  const float* bias  = (const float*)d_in[4];
  const float* a_dst = (const float*)d_in[6];

  char* ws = (char*)d_ws;
  const size_t PBsz = (size_t)128 * 8 * 1024;   // 1 MB
  const size_t EDsz = (size_t)N_TOK * NH * 2;   // 32 KB
  const size_t base = PBsz + EDsz;
  const size_t per_split = (size_t)N_TOK * OUTW * 4 + (size_t)N_TOK * NH * 4;

  unsigned short* PB  = (unsigned short*)ws;
  unsigned short* EDH = (unsigned short*)(ws + PBsz);
  float* op = (float*)(ws + base);
  float* outp = (float*)d_out;

  prep_kernel<<<N_TOK / NT, 128, 0, stream>>>(G, W, bias, a_dst, EDH, PB);
  if (ws_size >= base + 4 * per_split) {
    float* dp = (float*)(ws + base + 4 * (size_t)N_TOK * OUTW * 4);
    attn_kernel<4><<<(N_TOK / BT) * 4, 512, 0, stream>>>(A, EDH, PB, op, dp, nullptr);
    comb_kernel<<<(N_TOK * OUTW / 4) / 256, 256, 0, stream>>>(op, dp, outp, 4);
  } else if (ws_size >= base + 2 * per_split) {
    float* dp = (float*)(ws + base + 2 * (size_t)N_TOK * OUTW * 4);
    attn_kernel<2><<<(N_TOK / BT) * 2, 512, 0, stream>>>(A, EDH, PB, op, dp, nullptr);
    comb_kernel<<<(N_TOK * OUTW / 4) / 256, 256, 0, stream>>>(op, dp, outp, 2);
  } else {
    attn_kernel<1><<<N_TOK / BT, 512, 0, stream>>>(A, EDH, PB, nullptr, nullptr, outp);
  }
}

// Round 15
// 35.298 us; speedup vs baseline: 1.0054x; 1.0054x over previous
//
#include <hip/hip_runtime.h>
#include <stdint.h>

#define N_TOK 4096
#define D_IN  64
#define NF    32
#define NH    4
#define OUTW  (NH * NF)        // 128
#define NT    8
#define CHUNK 128              // n per chunk (4 k-steps of 32)
#define BT    32               // rows per block (2 rowgroups of 16)

typedef float        f32x4  __attribute__((ext_vector_type(4)));
typedef unsigned int uint4v __attribute__((ext_vector_type(4)));
typedef __bf16       bf16x8 __attribute__((ext_vector_type(8)));

union Frag { uint4v u; bf16x8 v; };

static __device__ __forceinline__ unsigned short f2bf_rne(float x) {
  unsigned u = __float_as_uint(x);
  u += 0x7fffu + ((u >> 16) & 1u);
  return (unsigned short)(u >> 16);
}
static __device__ __forceinline__ float bflo(unsigned x) {
  return __uint_as_float(x << 16);
}
static __device__ __forceinline__ float bfhi(unsigned x) {
  return __uint_as_float(x & 0xffff0000u);
}

// ---------- Kernel 1 (unchanged, proven): PB = WG2 frag-packed, EDH[h][n] ---
// PB 16-B slot ((t*8 + set)*64 + gq*16 + col): t = n>>5, gq = (n>>3)&3,
// set = h*2 + fhalf, col = f&15, 8 bf16 (j = n&7). Total 1 MB.
__global__ __launch_bounds__(128) void prep_kernel(
    const float* __restrict__ G, const float* __restrict__ W,
    const float* __restrict__ bias, const float* __restrict__ a_dst,
    unsigned short* __restrict__ EDH, unsigned short* __restrict__ PB) {
  __shared__ float gs[NT * D_IN];
  const int tid = threadIdx.x;
  const int n0  = blockIdx.x * NT;
  {
    const float4* src = (const float4*)(G + (size_t)n0 * D_IN);
    float4* dst = (float4*)gs;
    dst[tid] = src[tid];
  }
  __syncthreads();
  const int h = tid >> 5, f = tid & 31;
  float acc[NT];
  const float bb = bias[h * NF + f];
#pragma unroll
  for (int k = 0; k < NT; ++k) acc[k] = bb;
#pragma unroll
  for (int i = 0; i < D_IN; ++i) {
    const float wv = W[(h * D_IN + i) * NF + f];
#pragma unroll
    for (int k = 0; k < NT; ++k) acc[k] = fmaf(gs[k * D_IN + i], wv, acc[k]);
  }
  const float ad = a_dst[h * NF + f];
  float ev[NT];
#pragma unroll
  for (int k = 0; k < NT; ++k) {
    float s = acc[k] * ad;
    s += __shfl_xor(s, 1);  s += __shfl_xor(s, 2);  s += __shfl_xor(s, 4);
    s += __shfl_xor(s, 8);  s += __shfl_xor(s, 16);
    ev[k] = __expf(s);
  }
  const int t   = n0 >> 5;
  const int gq  = (n0 >> 3) & 3;
  const int set = (h << 1) | (f >> 4);
  const int col = f & 15;
  union { uint4 u4; unsigned short us[8]; } pk;
#pragma unroll
  for (int k = 0; k < NT; ++k) pk.us[k] = f2bf_rne(acc[k] * ev[k]);
  *(uint4*)(PB + (size_t)((((t * 8 + set) << 6) + (gq << 4) + col)) * 8) = pk.u4;
  if (f == 0) {
    union { uint4 u4; unsigned short us[8]; } pe;
#pragma unroll
    for (int k = 0; k < NT; ++k) pe.us[k] = f2bf_rne(ev[k]);
    *(uint4*)&EDH[(size_t)h * N_TOK + n0] = pe.u4;
  }
}

// ---------- Kernel 2: 256-thr blocks (4 waves), wave = 1 head (2 B-sets) ----
// Same algorithm/traffic as r12; 2x barrier domains per CU. Per iter: issue
// B(c)x8 + A(c+2)x4; vmcnt(12) -> exp(c+1) (16 vals/thread, den-FMA, pack,
// 2 swizzled ds_write); barrier; vmcnt(4); 8 ds_read (each feeds 2 MFMAs).
template <int NS>
__global__ __launch_bounds__(256) void attn_kernel(
    const float* __restrict__ A, const unsigned short* __restrict__ EDH,
    const unsigned short* __restrict__ PB, float* __restrict__ op,
    float* __restrict__ dp, float* __restrict__ out) {
  constexpr int NHALF  = N_TOK / NS;
  constexpr int NIT    = NHALF / CHUNK;
  constexpr int RINGSZ = BT * CHUNK * 2;                         // 8192 B
  __shared__ __align__(16) unsigned short ring[3 * BT * CHUNK];  // 24 KB
  __shared__ __align__(16) unsigned short EDt[NH * NHALF];       // 4 KB @NS=8
  __shared__ float denLds[BT * NH];                              // 512 B
  char* ringb = (char*)ring;

  const int tid  = threadIdx.x;
  const int lane = tid & 63;
  const int w    = tid >> 6;          // wave = head
  const int bid  = blockIdx.x;
  const int s    = bid & (NS - 1);
  const int b0   = (bid / NS) * BT;

  // staging coords: 256 thr = 32 rows x 8 col-groups of 16 floats
  const int srow = tid >> 3, tp = tid & 7;
  const float* abase = A + (size_t)(b0 + srow) * N_TOK + s * NHALF + tp * 16;
  const int wb0 = srow * 256 + (((2 * tp    ) ^ (srow & 15)) << 4);
  const int wb1 = srow * 256 + (((2 * tp + 1) ^ (srow & 15)) << 4);

  // MFMA frag coords
  const int rowm = lane & 15, g = lane >> 4;
  const char* pbb = (const char*)PB + (size_t)s * (NHALF / 32) * 8192;
  const char* pw0 = pbb + ((((2 * w    ) << 6) + lane) << 4);  // set h,fh=0
  const char* pw1 = pbb + ((((2 * w + 1) << 6) + lane) << 4);  // set h,fh=1

  { // EDH[h][s*NHALF ..] -> EDt[h][0..NHALF)
    const uint4* src = (const uint4*)EDH;
    uint4* dst = (uint4*)EDt;
    constexpr int tot = NH * NHALF / 8;
#pragma unroll 1
    for (int i = tid; i < tot; i += 256) {
      const int hh = i / (NHALF / 8), k = i % (NHALF / 8);
      dst[i] = src[hh * (N_TOK / 8) + s * (NHALF / 8) + k];
    }
  }
  __syncthreads();

  f32x4 ac00 = {0.f, 0.f, 0.f, 0.f}, ac01 = {0.f, 0.f, 0.f, 0.f};
  f32x4 ac10 = {0.f, 0.f, 0.f, 0.f}, ac11 = {0.f, 0.f, 0.f, 0.f};
  f32x4 dsum = {0.f, 0.f, 0.f, 0.f};
  f32x4 aXa, aXb, aXc, aXd, aYa, aYb, aYc, aYd;
  Frag f00, f01, f02, f03, f10, f11, f12, f13;  // B frags, single-buffered
  int mR = 0, mW = 1;

#define LOADA4(d0, d1, d2, d3, cc) do {                                        \
    const float* ap_ = abase + (size_t)(cc) * CHUNK;                           \
    asm volatile("global_load_dwordx4 %0, %1, off"                            \
                 : "=v"(d0) : "v"(ap_) : "memory");                            \
    asm volatile("global_load_dwordx4 %0, %1, off"                            \
                 : "=v"(d1) : "v"(ap_ + 4) : "memory");                        \
    asm volatile("global_load_dwordx4 %0, %1, off"                            \
                 : "=v"(d2) : "v"(ap_ + 8) : "memory");                        \
    asm volatile("global_load_dwordx4 %0, %1, off"                            \
                 : "=v"(d3) : "v"(ap_ + 12) : "memory");                       \
  } while (0)
#define LOADB0(fr, cc, kk)                                                     \
  asm volatile("global_load_dwordx4 %0, %1, off"                              \
               : "=v"(fr.u)                                                    \
               : "v"(pw0 + (size_t)((cc) * 4 + (kk)) * 8192) : "memory")
#define LOADB1(fr, cc, kk)                                                     \
  asm volatile("global_load_dwordx4 %0, %1, off"                              \
               : "=v"(fr.u)                                                    \
               : "v"(pw1 + (size_t)((cc) * 4 + (kk)) * 8192) : "memory")

// 8 values: exp + den-FMA (4 heads) + pack + one swizzled 16-B ring write
#define EXPH(P0, P1, eoff, wboff, cchunk, mw) do {                             \
    float x0 = __expf(-P0[0]), x1 = __expf(-P0[1]);                            \
    float x2 = __expf(-P0[2]), x3 = __expf(-P0[3]);                            \
    float x4 = __expf(-P1[0]), x5 = __expf(-P1[1]);                            \
    float x6 = __expf(-P1[2]), x7 = __expf(-P1[3]);                            \
    if ((cchunk) < NIT) {                                                      \
      uint4v e0_ = *(const uint4v*)&EDt[0 * NHALF + (eoff)];                   \
      uint4v e1_ = *(const uint4v*)&EDt[1 * NHALF + (eoff)];                   \
      uint4v e2_ = *(const uint4v*)&EDt[2 * NHALF + (eoff)];                   \
      uint4v e3_ = *(const uint4v*)&EDt[3 * NHALF + (eoff)];                   \
      dsum[0] = fmaf(x0, bflo(e0_[0]), dsum[0]);                               \
      dsum[0] = fmaf(x1, bfhi(e0_[0]), dsum[0]);                               \
      dsum[0] = fmaf(x2, bflo(e0_[1]), dsum[0]);                               \
      dsum[0] = fmaf(x3, bfhi(e0_[1]), dsum[0]);                               \
      dsum[0] = fmaf(x4, bflo(e0_[2]), dsum[0]);                               \
      dsum[0] = fmaf(x5, bfhi(e0_[2]), dsum[0]);                               \
      dsum[0] = fmaf(x6, bflo(e0_[3]), dsum[0]);                               \
      dsum[0] = fmaf(x7, bfhi(e0_[3]), dsum[0]);                               \
      dsum[1] = fmaf(x0, bflo(e1_[0]), dsum[1]);                               \
      dsum[1] = fmaf(x1, bfhi(e1_[0]), dsum[1]);                               \
      dsum[1] = fmaf(x2, bflo(e1_[1]), dsum[1]);                               \
      dsum[1] = fmaf(x3, bfhi(e1_[1]), dsum[1]);                               \
      dsum[1] = fmaf(x4, bflo(e1_[2]), dsum[1]);                               \
      dsum[1] = fmaf(x5, bfhi(e1_[2]), dsum[1]);                               \
      dsum[1] = fmaf(x6, bflo(e1_[3]), dsum[1]);                               \
      dsum[1] = fmaf(x7, bfhi(e1_[3]), dsum[1]);                               \
      dsum[2] = fmaf(x0, bflo(e2_[0]), dsum[2]);                               \
      dsum[2] = fmaf(x1, bfhi(e2_[0]), dsum[2]);                               \
      dsum[2] = fmaf(x2, bflo(e2_[1]), dsum[2]);                               \
      dsum[2] = fmaf(x3, bfhi(e2_[1]), dsum[2]);                               \
      dsum[2] = fmaf(x4, bflo(e2_[2]), dsum[2]);                               \
      dsum[2] = fmaf(x5, bfhi(e2_[2]), dsum[2]);                               \
      dsum[2] = fmaf(x6, bflo(e2_[3]), dsum[2]);                               \
      dsum[2] = fmaf(x7, bfhi(e2_[3]), dsum[2]);                               \
      dsum[3] = fmaf(x0, bflo(e3_[0]), dsum[3]);                               \
      dsum[3] = fmaf(x1, bfhi(e3_[0]), dsum[3]);                               \
      dsum[3] = fmaf(x2, bflo(e3_[1]), dsum[3]);                               \
      dsum[3] = fmaf(x3, bfhi(e3_[1]), dsum[3]);                               \
      dsum[3] = fmaf(x4, bflo(e3_[2]), dsum[3]);                               \
      dsum[3] = fmaf(x5, bfhi(e3_[2]), dsum[3]);                               \
      dsum[3] = fmaf(x6, bflo(e3_[3]), dsum[3]);                               \
      dsum[3] = fmaf(x7, bfhi(e3_[3]), dsum[3]);                               \
    }                                                                          \
    uint4v t_;                                                                 \
    t_[0] = __builtin_amdgcn_perm(__float_as_uint(x1), __float_as_uint(x0), 0x07060302u); \
    t_[1] = __builtin_amdgcn_perm(__float_as_uint(x3), __float_as_uint(x2), 0x07060302u); \
    t_[2] = __builtin_amdgcn_perm(__float_as_uint(x5), __float_as_uint(x4), 0x07060302u); \
    t_[3] = __builtin_amdgcn_perm(__float_as_uint(x7), __float_as_uint(x6), 0x07060302u); \
    *(uint4v*)(ringb + (mw) * RINGSZ + (wboff)) = t_;                          \
  } while (0)

#define EXPP(P0, P1, P2, P3, cchunk, mw) do {                                  \
    const int eo_ = (cchunk) < NIT ? (cchunk) * CHUNK + tp * 16 : 0;           \
    EXPH(P0, P1, eo_, wb0, cchunk, mw);                                        \
    EXPH(P2, P3, eo_ + 8, wb1, cchunk, mw);                                    \
  } while (0)

// one A-frag ds_read feeds both f-half MFMAs of the head
#define MSTEP2(AC0, AC1, rg, kk, FB0, FB1) do {                                \
    Frag af_;                                                                  \
    af_.v = *(const bf16x8*)(ringb + mR * RINGSZ + ((rg) * 16 + rowm) * 256 +  \
                             ((((kk) * 4 + g) ^ rowm) << 4));                  \
    AC0 = __builtin_amdgcn_mfma_f32_16x16x32_bf16(af_.v, FB0.v, AC0, 0, 0, 0); \
    AC1 = __builtin_amdgcn_mfma_f32_16x16x32_bf16(af_.v, FB1.v, AC1, 0, 0, 0); \
  } while (0)

// entry: outstanding [A(c+1)x4]. Issue B(c)x8, A(c+2)x4 -> 16.
// vmcnt(12) drains A(c+1); post-barrier vmcnt(4) drains B(c).
#define ITER(cc, AU0, AU1, AU2, AU3, AL0, AL1, AL2, AL3) do {                  \
    LOADB0(f00, cc, 0); LOADB0(f01, cc, 1);                                    \
    LOADB0(f02, cc, 2); LOADB0(f03, cc, 3);                                    \
    LOADB1(f10, cc, 0); LOADB1(f11, cc, 1);                                    \
    LOADB1(f12, cc, 2); LOADB1(f13, cc, 3);                                    \
    { const int ca_ = ((cc) + 2 < NIT) ? (cc) + 2 : NIT - 1;                   \
      LOADA4(AL0, AL1, AL2, AL3, ca_); }                                       \
    asm volatile("s_waitcnt vmcnt(12)" ::: "memory");                          \
    __builtin_amdgcn_sched_barrier(0);                                         \
    EXPP(AU0, AU1, AU2, AU3, (cc) + 1, mW);                                    \
    asm volatile("s_waitcnt lgkmcnt(0)" ::: "memory");                         \
    __builtin_amdgcn_sched_barrier(0);                                         \
    __builtin_amdgcn_s_barrier();                                              \
    asm volatile("s_waitcnt vmcnt(4)" ::: "memory");                           \
    __builtin_amdgcn_sched_barrier(0);                                         \
    MSTEP2(ac00, ac10, 0, 0, f00, f10); MSTEP2(ac01, ac11, 1, 0, f00, f10);    \
    MSTEP2(ac00, ac10, 0, 1, f01, f11); MSTEP2(ac01, ac11, 1, 1, f01, f11);    \
    MSTEP2(ac00, ac10, 0, 2, f02, f12); MSTEP2(ac01, ac11, 1, 2, f02, f12);    \
    MSTEP2(ac00, ac10, 0, 3, f03, f13); MSTEP2(ac01, ac11, 1, 3, f03, f13);    \
    mR = mW; mW = (mW + 1 == 3) ? 0 : mW + 1;                                  \
  } while (0)

  // prologue: A(0)x4, A(1)x4 = 8 outstanding; vmcnt(4) drains A(0); exp c0.
  LOADA4(aXa, aXb, aXc, aXd, 0);
  LOADA4(aYa, aYb, aYc, aYd, (1 < NIT) ? 1 : 0);
  asm volatile("s_waitcnt vmcnt(4)" ::: "memory");
  __builtin_amdgcn_sched_barrier(0);
  EXPP(aXa, aXb, aXc, aXd, 0, 0);

#pragma unroll 1
  for (int i = 0; i < NIT; i += 2) {
    ITER(i,     aYa, aYb, aYc, aYd, aXa, aXb, aXc, aXd);
    ITER(i + 1, aXa, aXb, aXc, aXd, aYa, aYb, aYc, aYd);
  }

  // drain in-flight asm loads before epilogue reuses their dest regs
  asm volatile("s_waitcnt vmcnt(0)" ::: "memory");
  __builtin_amdgcn_sched_barrier(0);

  // denominator: reduce over the 8 threads (tp) sharing a row
#pragma unroll
  for (int m = 1; m <= 4; m <<= 1) {
    dsum[0] += __shfl_xor(dsum[0], m);
    dsum[1] += __shfl_xor(dsum[1], m);
    dsum[2] += __shfl_xor(dsum[2], m);
    dsum[3] += __shfl_xor(dsum[3], m);
  }

  // C/D: row = rg*16 + g*4 + r, col = rowm. Wave w -> out cols w*32 + fh*16.
  if (NS == 1) {
    if (tp == 0) {
      float4 dv; dv.x = dsum[0]; dv.y = dsum[1]; dv.z = dsum[2]; dv.w = dsum[3];
      *(float4*)&denLds[srow * NH] = dv;
    }
    __syncthreads();
#pragma unroll
    for (int r = 0; r < 4; ++r) {
      const int rr = g * 4 + r;
      const float d0 = denLds[rr * NH + w];
      const float d1 = denLds[(16 + rr) * NH + w];
      float o;
      o = ac00[r] / d0;
      out[(size_t)(b0 + rr) * OUTW + w * 32 + rowm] = o > 0.f ? o : 0.f;
      o = ac01[r] / d1;
      out[(size_t)(b0 + 16 + rr) * OUTW + w * 32 + rowm] = o > 0.f ? o : 0.f;
      o = ac10[r] / d0;
      out[(size_t)(b0 + rr) * OUTW + w * 32 + 16 + rowm] = o > 0.f ? o : 0.f;
      o = ac11[r] / d1;
      out[(size_t)(b0 + 16 + rr) * OUTW + w * 32 + 16 + rowm] = o > 0.f ? o : 0.f;
    }
  } else {
    if (tp == 0) {
      float4 dv; dv.x = dsum[0]; dv.y = dsum[1]; dv.z = dsum[2]; dv.w = dsum[3];
      *(float4*)&dp[((size_t)s * N_TOK + b0 + srow) * NH] = dv;
    }
    float* ob = op + (size_t)s * (N_TOK * OUTW) + (size_t)b0 * OUTW + w * 32 + rowm;
#pragma unroll
    for (int r = 0; r < 4; ++r) {
      const int rr = g * 4 + r;
      ob[(size_t)rr * OUTW]             = ac00[r];
      ob[(size_t)(16 + rr) * OUTW]      = ac01[r];
      ob[(size_t)rr * OUTW + 16]        = ac10[r];
      ob[(size_t)(16 + rr) * OUTW + 16] = ac11[r];
    }
  }
#undef LOADA4
#undef LOADB0
#undef LOADB1
#undef EXPH
#undef EXPP
#undef MSTEP2
#undef ITER
}

// ---------- Kernel 3: combine splits, divide, relu ----------
__global__ __launch_bounds__(256) void comb_kernel(
    const float* __restrict__ op, const float* __restrict__ dp,
    float* __restrict__ out, int NS) {
  const int idx4 = blockIdx.x * 256 + threadIdx.x;
  const int eb = idx4 >> 5;
  const int h  = ((idx4 << 2) & 127) >> 5;
  float4 o; o.x = 0.f; o.y = 0.f; o.z = 0.f; o.w = 0.f;
  float d = 0.f;
  for (int s2 = 0; s2 < NS; ++s2) {
    float4 vv = *(const float4*)(op + (size_t)s2 * (N_TOK * OUTW) + (size_t)idx4 * 4);
    o.x += vv.x; o.y += vv.y; o.z += vv.z; o.w += vv.w;
    d += dp[((size_t)s2 * N_TOK + eb) * NH + h];
  }
  const float r = 1.f / d;
  float4 res;
  res.x = fmaxf(o.x * r, 0.f);
  res.y = fmaxf(o.y * r, 0.f);
  res.z = fmaxf(o.z * r, 0.f);
  res.w = fmaxf(o.w * r, 0.f);
  *(float4*)(out + (size_t)idx4 * 4) = res;
}

extern "C" void kernel_launch(void* const* d_in, const int* in_sizes, int n_in,
                              void* d_out, int out_size, void* d_ws, size_t ws_size,
                              hipStream_t stream) {
  // inputs: 0=X(unused) 1=G 2=A 3=W 4=b 5=a_src(unused) 6=a_dst 7=att_b(unused)
  const float* G     = (const float*)d_in[1];
  const float* A     = (const float*)d_in[2];
  const float* W     = (const float*)d_in[3];
  const float* bias  = (const float*)d_in[4];
  const float* a_dst = (const float*)d_in[6];

  char* ws = (char*)d_ws;
  const size_t PBsz = (size_t)128 * 8 * 1024;   // 1 MB
  const size_t EDsz = (size_t)N_TOK * NH * 2;   // 32 KB
  const size_t base = PBsz + EDsz;
  const size_t per_split = (size_t)N_TOK * OUTW * 4 + (size_t)N_TOK * NH * 4;

  unsigned short* PB  = (unsigned short*)ws;
  unsigned short* EDH = (unsigned short*)(ws + PBsz);
  float* op = (float*)(ws + base);
  float* outp = (float*)d_out;

  prep_kernel<<<N_TOK / NT, 128, 0, stream>>>(G, W, bias, a_dst, EDH, PB);
  if (ws_size >= base + 8 * per_split) {
    float* dp = (float*)(ws + base + 8 * (size_t)N_TOK * OUTW * 4);
    attn_kernel<8><<<(N_TOK / BT) * 8, 256, 0, stream>>>(A, EDH, PB, op, dp, nullptr);
    comb_kernel<<<(N_TOK * OUTW / 4) / 256, 256, 0, stream>>>(op, dp, outp, 8);
  } else if (ws_size >= base + 4 * per_split) {
    float* dp = (float*)(ws + base + 4 * (size_t)N_TOK * OUTW * 4);
    attn_kernel<4><<<(N_TOK / BT) * 4, 256, 0, stream>>>(A, EDH, PB, op, dp, nullptr);
    comb_kernel<<<(N_TOK * OUTW / 4) / 256, 256, 0, stream>>>(op, dp, outp, 4);
  } else if (ws_size >= base + 2 * per_split) {
    float* dp = (float*)(ws + base + 2 * (size_t)N_TOK * OUTW * 4);
    attn_kernel<2><<<(N_TOK / BT) * 2, 256, 0, stream>>>(A, EDH, PB, op, dp, nullptr);
    comb_kernel<<<(N_TOK * OUTW / 4) / 256, 256, 0, stream>>>(op, dp, outp, 2);
  } else {
    attn_kernel<1><<<N_TOK / BT, 256, 0, stream>>>(A, EDH, PB, nullptr, nullptr, outp);
  }
}

// Round 16
// 30.980 us; speedup vs baseline: 1.1456x; 1.1394x over previous
//
#include <hip/hip_runtime.h>
#include <stdint.h>

#define N_TOK 4096
#define D_IN  64
#define NF    32
#define NH    4
#define OUTW  (NH * NF)        // 128
#define NT    8
#define CHUNK 128              // n per chunk (4 k-steps of 32)
#define BT    32               // rows per block (2 rowgroups of 16)

typedef float        f32x4  __attribute__((ext_vector_type(4)));
typedef unsigned int uint4v __attribute__((ext_vector_type(4)));
typedef __bf16       bf16x8 __attribute__((ext_vector_type(8)));

union Frag { uint4v u; bf16x8 v; };

static __device__ __forceinline__ unsigned short f2bf_rne(float x) {
  unsigned u = __float_as_uint(x);
  u += 0x7fffu + ((u >> 16) & 1u);
  return (unsigned short)(u >> 16);
}

// ---------- Kernel 1 (r9-proven): PB = [WG2 | ED] fragment-packed ----------
// PB 16-B slot ((t*9 + set)*64 + gq*16 + col): t = n>>5, gq = (n>>3)&3,
// set<8: h*2+fhalf, col = f&15; set==8: den-frag (col<4 -> ED[n][col], else 0).
__global__ __launch_bounds__(128) void prep_kernel(
    const float* __restrict__ G, const float* __restrict__ W,
    const float* __restrict__ bias, const float* __restrict__ a_dst,
    unsigned short* __restrict__ PB) {
  __shared__ float gs[NT * D_IN];
  const int tid = threadIdx.x;
  const int n0  = blockIdx.x * NT;
  {
    const float4* src = (const float4*)(G + (size_t)n0 * D_IN);
    float4* dst = (float4*)gs;
    dst[tid] = src[tid];
  }
  __syncthreads();
  const int h = tid >> 5, f = tid & 31;
  float acc[NT];
  const float bb = bias[h * NF + f];
#pragma unroll
  for (int k = 0; k < NT; ++k) acc[k] = bb;
#pragma unroll
  for (int i = 0; i < D_IN; ++i) {
    const float wv = W[(h * D_IN + i) * NF + f];
#pragma unroll
    for (int k = 0; k < NT; ++k) acc[k] = fmaf(gs[k * D_IN + i], wv, acc[k]);
  }
  const float ad = a_dst[h * NF + f];
  float ev[NT];
#pragma unroll
  for (int k = 0; k < NT; ++k) {
    float s = acc[k] * ad;
    s += __shfl_xor(s, 1);  s += __shfl_xor(s, 2);  s += __shfl_xor(s, 4);
    s += __shfl_xor(s, 8);  s += __shfl_xor(s, 16);
    ev[k] = __expf(s);
  }
  const int t   = n0 >> 5;
  const int gq  = (n0 >> 3) & 3;
  const int set = (h << 1) | (f >> 4);
  const int col = f & 15;
  union { uint4 u4; unsigned short us[8]; } pk;
#pragma unroll
  for (int k = 0; k < NT; ++k) pk.us[k] = f2bf_rne(acc[k] * ev[k]);
  *(uint4*)(PB + (size_t)((((t * 9 + set) << 6) + (gq << 4) + col)) * 8) = pk.u4;
  if (f == 0) {
    union { uint4 u4; unsigned short us[8]; } pe;
#pragma unroll
    for (int k = 0; k < NT; ++k) pe.us[k] = f2bf_rne(ev[k]);
    *(uint4*)(PB + (size_t)((((t * 9 + 8) << 6) + (gq << 4) + h)) * 8) = pe.u4;
  }
  if (h == 0 && f >= 4 && f < 16) {
    uint4 z; z.x = 0u; z.y = 0u; z.z = 0u; z.w = 0u;
    *(uint4*)(PB + (size_t)((((t * 9 + 8) << 6) + (gq << 4) + f)) * 8) = z;
  }
}

// ---------- Kernel 2: r9 pipeline (best measured) + T5 setprio on MFMAs -----
// grid = (4096/32)*NS, 512 thr (8 waves = sets). Wave 0 additionally computes
// the denominator via its own den-frag double buffer. w0 queue: vmcnt(10);
// w>0 queue: vmcnt(6). One barrier/iter; vmcnt(0) drain before epilogue.
template <int NS>
__global__ __launch_bounds__(512) void attn_kernel(
    const float* __restrict__ A, const unsigned short* __restrict__ PB,
    float* __restrict__ op, float* __restrict__ dp, float* __restrict__ out) {
  constexpr int NHALF  = N_TOK / NS;
  constexpr int NIT    = NHALF / CHUNK;
  constexpr int RINGSZ = BT * CHUNK * 2;               // 8192 B
  __shared__ __align__(16) unsigned short ring[3 * BT * CHUNK];  // 24 KB
  __shared__ float denLds[BT * NH];                    // 512 B
  char* ringb = (char*)ring;

  const int tid  = threadIdx.x;
  const int lane = tid & 63;
  const int w    = tid >> 6;
  const int bid  = blockIdx.x;
  const int s    = bid & (NS - 1);
  const int b0   = (bid / NS) * BT;

  // staging coords: 512 thr = 32 rows x 16 col-groups of 8
  const int srow = tid >> 4, tp = tid & 15;
  const float* abase = A + (size_t)(b0 + srow) * N_TOK + s * NHALF + tp * 8;
  const int wb0 = srow * 256 + ((tp ^ (srow & 15)) << 4);  // swizzled 16-B slot

  // MFMA frag coords
  const int rowm = lane & 15, g = lane >> 4;
  const char* pbb  = (const char*)PB + (size_t)s * (NHALF / 32) * 9216;
  const char* pown = pbb + (((w << 6) + lane) << 4);
  const char* pden = pbb + (((8 << 6) + lane) << 4);

  f32x4 acc0  = {0.f, 0.f, 0.f, 0.f}, acc1  = {0.f, 0.f, 0.f, 0.f};
  f32x4 accd0 = {0.f, 0.f, 0.f, 0.f}, accd1 = {0.f, 0.f, 0.f, 0.f};
  f32x4 aXa, aXb, aYa, aYb;
  Frag bo0, bo1, bo2, bo3, bd0, bd1, bd2, bd3;
  Frag co0, co1, co2, co3, cd0, cd1, cd2, cd3;
  int mR = 0, mW = 1;

#define LOADA2(d0, d1, cc) do {                                                \
    const float* ap_ = abase + (size_t)(cc) * CHUNK;                           \
    asm volatile("global_load_dwordx4 %0, %1, off"                            \
                 : "=v"(d0) : "v"(ap_) : "memory");                            \
    asm volatile("global_load_dwordx4 %0, %1, off"                            \
                 : "=v"(d1) : "v"(ap_ + 4) : "memory");                        \
  } while (0)
#define LOADBO(fr, cc, kk)                                                     \
  asm volatile("global_load_dwordx4 %0, %1, off"                              \
               : "=v"(fr.u)                                                    \
               : "v"(pown + (size_t)((cc) * 4 + (kk)) * 9216) : "memory")
#define LOADBD(fr, cc, kk)                                                     \
  asm volatile("global_load_dwordx4 %0, %1, off"                              \
               : "=v"(fr.u)                                                    \
               : "v"(pden + (size_t)((cc) * 4 + (kk)) * 9216) : "memory")

#define EXPP(AV0, AV1, mw) do {                                                \
    float x0 = __expf(-AV0[0]), x1 = __expf(-AV0[1]);                          \
    float x2 = __expf(-AV0[2]), x3 = __expf(-AV0[3]);                          \
    float x4 = __expf(-AV1[0]), x5 = __expf(-AV1[1]);                          \
    float x6 = __expf(-AV1[2]), x7 = __expf(-AV1[3]);                          \
    uint4v t_;                                                                 \
    t_[0] = __builtin_amdgcn_perm(__float_as_uint(x1), __float_as_uint(x0), 0x07060302u); \
    t_[1] = __builtin_amdgcn_perm(__float_as_uint(x3), __float_as_uint(x2), 0x07060302u); \
    t_[2] = __builtin_amdgcn_perm(__float_as_uint(x5), __float_as_uint(x4), 0x07060302u); \
    t_[3] = __builtin_amdgcn_perm(__float_as_uint(x7), __float_as_uint(x6), 0x07060302u); \
    *(uint4v*)(ringb + (mw) * RINGSZ + wb0) = t_;                              \
  } while (0)

// own+den MFMA pair (wave 0)
#define MSTEPD(rg, kk, FB, FD) do {                                            \
    Frag af_;                                                                  \
    af_.v = *(const bf16x8*)(ringb + mR * RINGSZ + ((rg) * 16 + rowm) * 256 +  \
                             ((((kk) * 4 + g) ^ rowm) << 4));                  \
    if ((rg) == 0) {                                                           \
      acc0  = __builtin_amdgcn_mfma_f32_16x16x32_bf16(af_.v, FB.v, acc0,  0, 0, 0); \
      accd0 = __builtin_amdgcn_mfma_f32_16x16x32_bf16(af_.v, FD.v, accd0, 0, 0, 0); \
    } else {                                                                   \
      acc1  = __builtin_amdgcn_mfma_f32_16x16x32_bf16(af_.v, FB.v, acc1,  0, 0, 0); \
      accd1 = __builtin_amdgcn_mfma_f32_16x16x32_bf16(af_.v, FD.v, accd1, 0, 0, 0); \
    }                                                                          \
  } while (0)
// own-only MFMA (waves 1..7)
#define MSTEPO(rg, kk, FB) do {                                                \
    Frag af_;                                                                  \
    af_.v = *(const bf16x8*)(ringb + mR * RINGSZ + ((rg) * 16 + rowm) * 256 +  \
                             ((((kk) * 4 + g) ^ rowm) << 4));                  \
    if ((rg) == 0)                                                             \
      acc0 = __builtin_amdgcn_mfma_f32_16x16x32_bf16(af_.v, FB.v, acc0, 0, 0, 0); \
    else                                                                       \
      acc1 = __builtin_amdgcn_mfma_f32_16x16x32_bf16(af_.v, FB.v, acc1, 0, 0, 0); \
  } while (0)

// wave 0: steady entry [B(c)x8, A(c+1)x2] = 10; issue 10; vmcnt(10)
#define ITERD(cc, AC0, AC1, AN0, AN1, CO0, CO1, CO2, CO3, CD0, CD1, CD2, CD3,  \
              NO0, NO1, NO2, NO3, ND0, ND1, ND2, ND3) do {                     \
    { const int cb_ = ((cc) + 1 < NIT) ? (cc) + 1 : NIT - 1;                   \
      LOADBO(NO0, cb_, 0); LOADBO(NO1, cb_, 1);                                \
      LOADBO(NO2, cb_, 2); LOADBO(NO3, cb_, 3);                                \
      LOADBD(ND0, cb_, 0); LOADBD(ND1, cb_, 1);                                \
      LOADBD(ND2, cb_, 2); LOADBD(ND3, cb_, 3); }                              \
    { const int ca_ = ((cc) + 2 < NIT) ? (cc) + 2 : NIT - 1;                   \
      LOADA2(AN0, AN1, ca_); }                                                 \
    asm volatile("s_waitcnt vmcnt(10)" ::: "memory");                          \
    __builtin_amdgcn_sched_barrier(0);                                         \
    EXPP(AC0, AC1, mW);                                                        \
    asm volatile("s_waitcnt lgkmcnt(0)" ::: "memory");                         \
    __builtin_amdgcn_sched_barrier(0);                                         \
    __builtin_amdgcn_s_barrier();                                              \
    __builtin_amdgcn_s_setprio(1);                                             \
    MSTEPD(0, 0, CO0, CD0); MSTEPD(1, 0, CO0, CD0);                            \
    MSTEPD(0, 1, CO1, CD1); MSTEPD(1, 1, CO1, CD1);                            \
    MSTEPD(0, 2, CO2, CD2); MSTEPD(1, 2, CO2, CD2);                            \
    MSTEPD(0, 3, CO3, CD3); MSTEPD(1, 3, CO3, CD3);                            \
    __builtin_amdgcn_s_setprio(0);                                             \
    mR = mW; mW = (mW + 1 == 3) ? 0 : mW + 1;                                  \
  } while (0)
// waves 1..7: steady entry [B(c)x4, A(c+1)x2] = 6; issue 6; vmcnt(6)
#define ITERO(cc, AC0, AC1, AN0, AN1, CO0, CO1, CO2, CO3,                      \
              NO0, NO1, NO2, NO3) do {                                         \
    { const int cb_ = ((cc) + 1 < NIT) ? (cc) + 1 : NIT - 1;                   \
      LOADBO(NO0, cb_, 0); LOADBO(NO1, cb_, 1);                                \
      LOADBO(NO2, cb_, 2); LOADBO(NO3, cb_, 3); }                              \
    { const int ca_ = ((cc) + 2 < NIT) ? (cc) + 2 : NIT - 1;                   \
      LOADA2(AN0, AN1, ca_); }                                                 \
    asm volatile("s_waitcnt vmcnt(6)" ::: "memory");                           \
    __builtin_amdgcn_sched_barrier(0);                                         \
    EXPP(AC0, AC1, mW);                                                        \
    asm volatile("s_waitcnt lgkmcnt(0)" ::: "memory");                         \
    __builtin_amdgcn_sched_barrier(0);                                         \
    __builtin_amdgcn_s_barrier();                                              \
    __builtin_amdgcn_s_setprio(1);                                             \
    MSTEPO(0, 0, CO0); MSTEPO(1, 0, CO0);                                      \
    MSTEPO(0, 1, CO1); MSTEPO(1, 1, CO1);                                      \
    MSTEPO(0, 2, CO2); MSTEPO(1, 2, CO2);                                      \
    MSTEPO(0, 3, CO3); MSTEPO(1, 3, CO3);                                      \
    __builtin_amdgcn_s_setprio(0);                                             \
    mR = mW; mW = (mW + 1 == 3) ? 0 : mW + 1;                                  \
  } while (0)

  if (w == 0) {
    // prologue: [A(0)x2, B(0)x8, A(1)x2] = 12; vmcnt(10) drains A(0)
    LOADA2(aXa, aXb, 0);
    LOADBO(bo0, 0, 0); LOADBO(bo1, 0, 1); LOADBO(bo2, 0, 2); LOADBO(bo3, 0, 3);
    LOADBD(bd0, 0, 0); LOADBD(bd1, 0, 1); LOADBD(bd2, 0, 2); LOADBD(bd3, 0, 3);
    LOADA2(aYa, aYb, 1);
    asm volatile("s_waitcnt vmcnt(10)" ::: "memory");
    __builtin_amdgcn_sched_barrier(0);
    EXPP(aXa, aXb, 0);
#pragma unroll 1
    for (int i = 0; i < NIT; i += 2) {
      ITERD(i,     aYa, aYb, aXa, aXb, bo0, bo1, bo2, bo3, bd0, bd1, bd2, bd3,
                                       co0, co1, co2, co3, cd0, cd1, cd2, cd3);
      ITERD(i + 1, aXa, aXb, aYa, aYb, co0, co1, co2, co3, cd0, cd1, cd2, cd3,
                                       bo0, bo1, bo2, bo3, bd0, bd1, bd2, bd3);
    }
  } else {
    // prologue: [A(0)x2, B(0)x4, A(1)x2] = 8; vmcnt(6) drains A(0)
    LOADA2(aXa, aXb, 0);
    LOADBO(bo0, 0, 0); LOADBO(bo1, 0, 1); LOADBO(bo2, 0, 2); LOADBO(bo3, 0, 3);
    LOADA2(aYa, aYb, 1);
    asm volatile("s_waitcnt vmcnt(6)" ::: "memory");
    __builtin_amdgcn_sched_barrier(0);
    EXPP(aXa, aXb, 0);
#pragma unroll 1
    for (int i = 0; i < NIT; i += 2) {
      ITERO(i,     aYa, aYb, aXa, aXb, bo0, bo1, bo2, bo3,
                                       co0, co1, co2, co3);
      ITERO(i + 1, aXa, aXb, aYa, aYb, co0, co1, co2, co3,
                                       bo0, bo1, bo2, bo3);
    }
  }

  // drain in-flight asm loads before epilogue reuses their dest regs
  asm volatile("s_waitcnt vmcnt(0)" ::: "memory");
  __builtin_amdgcn_sched_barrier(0);

  // C/D: row = rg*16 + g*4 + r, col = rowm. Wave w covers output cols w*16+.
  // accd (wave 0) col h = denominator for head h.
  if (NS == 1) {
    if (w == 0 && rowm < NH) {
#pragma unroll
      for (int r = 0; r < 4; ++r) {
        denLds[(g * 4 + r) * NH + rowm]      = accd0[r];
        denLds[(16 + g * 4 + r) * NH + rowm] = accd1[r];
      }
    }
    __syncthreads();
    const int hh = w >> 1;
#pragma unroll
    for (int r = 0; r < 4; ++r) {
      const float o0 = acc0[r] / denLds[(g * 4 + r) * NH + hh];
      out[(size_t)(b0 + g * 4 + r) * OUTW + w * 16 + rowm] = o0 > 0.f ? o0 : 0.f;
      const float o1 = acc1[r] / denLds[(16 + g * 4 + r) * NH + hh];
      out[(size_t)(b0 + 16 + g * 4 + r) * OUTW + w * 16 + rowm] = o1 > 0.f ? o1 : 0.f;
    }
  } else {
    float* ob = op + (size_t)s * (N_TOK * OUTW) + (size_t)b0 * OUTW + w * 16 + rowm;
#pragma unroll
    for (int r = 0; r < 4; ++r) {
      ob[(size_t)(g * 4 + r) * OUTW]      = acc0[r];
      ob[(size_t)(16 + g * 4 + r) * OUTW] = acc1[r];
    }
    if (w == 0 && rowm < NH) {
#pragma unroll
      for (int r = 0; r < 4; ++r) {
        dp[((size_t)s * N_TOK + b0 + g * 4 + r) * NH + rowm]      = accd0[r];
        dp[((size_t)s * N_TOK + b0 + 16 + g * 4 + r) * NH + rowm] = accd1[r];
      }
    }
  }
#undef LOADA2
#undef LOADBO
#undef LOADBD
#undef EXPP
#undef MSTEPD
#undef MSTEPO
#undef ITERD
#undef ITERO
}

// ---------- Kernel 3: combine splits, divide, relu ----------
__global__ __launch_bounds__(256) void comb_kernel(
    const float* __restrict__ op, const float* __restrict__ dp,
    float* __restrict__ out, int NS) {
  const int idx4 = blockIdx.x * 256 + threadIdx.x;
  const int eb = idx4 >> 5;
  const int h  = ((idx4 << 2) & 127) >> 5;
  float4 o; o.x = 0.f; o.y = 0.f; o.z = 0.f; o.w = 0.f;
  float d = 0.f;
  for (int s2 = 0; s2 < NS; ++s2) {
    float4 vv = *(const float4*)(op + (size_t)s2 * (N_TOK * OUTW) + (size_t)idx4 * 4);
    o.x += vv.x; o.y += vv.y; o.z += vv.z; o.w += vv.w;
    d += dp[((size_t)s2 * N_TOK + eb) * NH + h];
  }
  const float r = 1.f / d;
  float4 res;
  res.x = fmaxf(o.x * r, 0.f);
  res.y = fmaxf(o.y * r, 0.f);
  res.z = fmaxf(o.z * r, 0.f);
  res.w = fmaxf(o.w * r, 0.f);
  *(float4*)(out + (size_t)idx4 * 4) = res;
}

extern "C" void kernel_launch(void* const* d_in, const int* in_sizes, int n_in,
                              void* d_out, int out_size, void* d_ws, size_t ws_size,
                              hipStream_t stream) {
  // inputs: 0=X(unused) 1=G 2=A 3=W 4=b 5=a_src(unused) 6=a_dst 7=att_b(unused)
  const float* G     = (const float*)d_in[1];
  const float* A     = (const float*)d_in[2];
  const float* W     = (const float*)d_in[3];
  const float* bias  = (const float*)d_in[4];
  const float* a_dst = (const float*)d_in[6];

  char* ws = (char*)d_ws;
  const size_t PBsz = (size_t)128 * 9 * 1024;  // 1,179,648 B
  const size_t per_split = (size_t)N_TOK * OUTW * 4 + (size_t)N_TOK * NH * 4;

  unsigned short* PB = (unsigned short*)ws;
  float* op = (float*)(ws + PBsz);
  float* outp = (float*)d_out;

  prep_kernel<<<N_TOK / NT, 128, 0, stream>>>(G, W, bias, a_dst, PB);
  if (ws_size >= PBsz + 4 * per_split) {
    float* dp = (float*)(ws + PBsz + 4 * (size_t)N_TOK * OUTW * 4);
    attn_kernel<4><<<(N_TOK / BT) * 4, 512, 0, stream>>>(A, PB, op, dp, nullptr);
    comb_kernel<<<(N_TOK * OUTW / 4) / 256, 256, 0, stream>>>(op, dp, outp, 4);
  } else if (ws_size >= PBsz + 2 * per_split) {
    float* dp = (float*)(ws + PBsz + 2 * (size_t)N_TOK * OUTW * 4);
    attn_kernel<2><<<(N_TOK / BT) * 2, 512, 0, stream>>>(A, PB, op, dp, nullptr);
    comb_kernel<<<(N_TOK * OUTW / 4) / 256, 256, 0, stream>>>(op, dp, outp, 2);
  } else {
    attn_kernel<1><<<N_TOK / BT, 512, 0, stream>>>(A, PB, nullptr, nullptr, outp);
  }
}